// Round 1
// baseline (415.305 us; speedup 1.0000x reference)
//
#include <hip/hip_runtime.h>
#include <hip/hip_bf16.h>

#define N 8192
#define D 128
#define BM 128
#define BN 128

typedef __bf16 bf16x8 __attribute__((ext_vector_type(8)));
typedef __bf16 bf16x2 __attribute__((ext_vector_type(2)));
typedef float f32x4 __attribute__((ext_vector_type(4)));

// Prep: Wb = bf16(W) ; sq[i] = sum_k W[i][k]^2 ; copy W to out+1 ; zero out[0]
__global__ __launch_bounds__(256) void prep_kernel(const float* __restrict__ W,
                                                   float* __restrict__ out,
                                                   float* __restrict__ sq,
                                                   __bf16* __restrict__ Wb) {
    const int wave = threadIdx.x >> 6;
    const int lane = threadIdx.x & 63;
    const int row = blockIdx.x * 4 + wave;
    const size_t base = (size_t)row * D + lane * 2;
    const float2 v = *(const float2*)(&W[base]);
    out[1 + base] = v.x;           // out+1 is only 4B-aligned; scalar stores
    out[2 + base] = v.y;
    bf16x2 b;
    b[0] = (__bf16)v.x;
    b[1] = (__bf16)v.y;
    *(bf16x2*)(&Wb[base]) = b;
    float s = v.x * v.x + v.y * v.y;
    for (int off = 32; off > 0; off >>= 1) s += __shfl_down(s, off, 64);
    if (lane == 0) sq[row] = s;
    if (row == 0 && threadIdx.x == 0) out[0] = 0.0f;
}

// Fused, barrier-free 128x128 tile per block:
//   Gram fragments read DIRECTLY from L2-resident Wb (no LDS staging, no barrier);
//   dist computed in-register from the MFMA C/D layout and immediately contracted
//   against per-element A loads (64B sectors fully utilized). No LDS round-trip,
//   no vmcnt(0) drain anywhere in the data path -> A loads stay in flight.
__global__ __launch_bounds__(256, 3) void lap_kernel(const float* __restrict__ A,
                                                     const __bf16* __restrict__ Wb,
                                                     const float* __restrict__ sq,
                                                     float* __restrict__ out) {
    __shared__ float red[4];

    const int tid = threadIdx.x;
    const int wave = tid >> 6;
    const int lane = tid & 63;
    const int l15 = lane & 15;
    const int quad = lane >> 4;
    const int wr = (wave >> 1) * 64;      // wave's 64x64 quadrant of the 128x128 tile
    const int wc = (wave & 1) * 64;
    const int i0 = (int)(blockIdx.x >> 6) * BM;
    const int j0 = (int)(blockIdx.x & 63) * BN;

    // ---- 1) Gram: fragments straight from global (Wb = 2MB, L2-resident) ----
    // frag layout per lane: row index = l15, k = quad*8 + j  (16B contiguous)
    f32x4 acc[4][4] = {};
#pragma unroll
    for (int kc = 0; kc < 4; ++kc) {
        bf16x8 a[4], b[4];
#pragma unroll
        for (int t = 0; t < 4; ++t)
            a[t] = *(const bf16x8*)(&Wb[(size_t)(i0 + wr + t * 16 + l15) * D + kc * 32 + quad * 8]);
#pragma unroll
        for (int t = 0; t < 4; ++t)
            b[t] = *(const bf16x8*)(&Wb[(size_t)(j0 + wc + t * 16 + l15) * D + kc * 32 + quad * 8]);
#pragma unroll
        for (int ti = 0; ti < 4; ++ti)
#pragma unroll
            for (int tj = 0; tj < 4; ++tj)
                acc[ti][tj] = __builtin_amdgcn_mfma_f32_16x16x32_bf16(a[ti], b[tj], acc[ti][tj], 0, 0, 0);
    }

    // ---- 2) fused dist + A contraction in the C/D layout ----
    // C/D mapping (m89-verified): col = l15, row = quad*4 + reg
    float sqj[4];
#pragma unroll
    for (int tj = 0; tj < 4; ++tj) sqj[tj] = sq[j0 + wc + tj * 16 + l15];

    float part0 = 0.0f, part1 = 0.0f;
#pragma unroll
    for (int ti = 0; ti < 4; ++ti) {
        float av[4][4];   // [r][tj]
        float sqi[4];
#pragma unroll
        for (int r = 0; r < 4; ++r) {
            const int row = i0 + wr + ti * 16 + quad * 4 + r;
            sqi[r] = sq[row];
            const float* Ar = A + (size_t)row * N + (j0 + wc + l15);
#pragma unroll
            for (int tj = 0; tj < 4; ++tj)
                av[r][tj] = Ar[tj * 16];          // tj*64B folds into the imm offset
        }
#pragma unroll
        for (int tj = 0; tj < 4; ++tj)
#pragma unroll
            for (int r = 0; r < 4; ++r) {
                const float d2 = fmaf(-2.0f, acc[ti][tj][r], sqi[r] + sqj[tj]);
                const float dist = __builtin_amdgcn_sqrtf(fmaxf(d2, 0.0f));
                if (r & 1) part1 = fmaf(av[r][tj], dist, part1);
                else       part0 = fmaf(av[r][tj], dist, part0);
            }
    }
    float local = part0 + part1;

    // ---- 3) block reduce + one atomic per block ----
    for (int off = 32; off > 0; off >>= 1) local += __shfl_down(local, off, 64);
    if (lane == 0) red[wave] = local;
    __syncthreads();
    if (tid == 0) atomicAdd(out, red[0] + red[1] + red[2] + red[3]);
}

extern "C" void kernel_launch(void* const* d_in, const int* in_sizes, int n_in,
                              void* d_out, int out_size, void* d_ws, size_t ws_size,
                              hipStream_t stream) {
    const float* A = (const float*)d_in[0];
    const float* W = (const float*)d_in[1];
    float* out = (float*)d_out;
    float* sq = (float*)d_ws;                         // 32 KB
    __bf16* Wb = (__bf16*)((char*)d_ws + 32 * 1024);  // 2 MB

    prep_kernel<<<N / 4, 256, 0, stream>>>(W, out, sq, Wb);
    lap_kernel<<<4096, 256, 0, stream>>>(A, Wb, sq, out);
}

// Round 2
// 374.916 us; speedup vs baseline: 1.1077x; 1.1077x over previous
//
#include <hip/hip_runtime.h>
#include <hip/hip_bf16.h>

#define N 8192
#define D 128
#define BM 128
#define BN 128
#define WSTR 136   // bf16 LDS stride: 272 B/row -> 16B-aligned b128, 2-way banks (free)
#define TJ 8       // j-tiles per block; grid = 64 * 8 = 512 = exactly 2 blocks/CU

typedef __bf16 bf16x8 __attribute__((ext_vector_type(8)));
typedef __bf16 bf16x4 __attribute__((ext_vector_type(4)));
typedef __bf16 bf16x2 __attribute__((ext_vector_type(2)));
typedef float f32x4 __attribute__((ext_vector_type(4)));

// Prep: Wb = bf16(W) ; sq[i] = sum_k W[i][k]^2 ; copy W to out+1 ; zero out[0]
__global__ __launch_bounds__(256) void prep_kernel(const float* __restrict__ W,
                                                   float* __restrict__ out,
                                                   float* __restrict__ sq,
                                                   __bf16* __restrict__ Wb) {
    const int wave = threadIdx.x >> 6;
    const int lane = threadIdx.x & 63;
    const int row = blockIdx.x * 4 + wave;
    const size_t base = (size_t)row * D + lane * 2;
    const float2 v = *(const float2*)(&W[base]);
    out[1 + base] = v.x;           // out+1 is only 4B-aligned; scalar stores
    out[2 + base] = v.y;
    bf16x2 b;
    b[0] = (__bf16)v.x;
    b[1] = (__bf16)v.y;
    *(bf16x2*)(&Wb[base]) = b;
    float s = v.x * v.x + v.y * v.y;
    for (int off = 32; off > 0; off >>= 1) s += __shfl_down(s, off, 64);
    if (lane == 0) sq[row] = s;
    if (row == 0 && threadIdx.x == 0) out[0] = 0.0f;
}

// Pipelined j-loop per block (round-0 tile code + raw barriers + counted vmcnt):
//   Wi staged once; per j-tile: Gram -> dist overlays Wj -> consume vs av regs.
//   A(t+1) issued right after consume(t); raw s_barrier (no vmcnt(0) drain) lets
//   the 16 float4 A loads stay in flight across stage/Gram/dist of tile t+1.
__global__ __launch_bounds__(256, 2) void lap_kernel(const float* __restrict__ A,
                                                     const __bf16* __restrict__ Wb,
                                                     const float* __restrict__ sq,
                                                     float* __restrict__ out) {
    __shared__ __align__(16) __bf16 ldsW[2 * BM * WSTR];   // Wi | Wj(=dist overlay) = 69.6 KB
    __bf16* ldsWj = ldsW + BM * WSTR;
    __shared__ float red[4];

    const int tid = threadIdx.x;
    const int wave = tid >> 6;
    const int lane = tid & 63;
    const int l15 = lane & 15;
    const int quad = lane >> 4;
    const int wr = (wave >> 1) * 64;
    const int wc = (wave & 1) * 64;
    const int i0 = (int)(blockIdx.x >> 3) * BM;   // 64 i-tiles
    const int jb = (int)(blockIdx.x & 7) * TJ;    // 8 j-groups of TJ tiles

    const int r8 = tid >> 5;          // 0..7
    const int c4 = (tid & 31) * 4;    // 0,4,...,124

    // ---- prologue: stage Wi + Wj(0) (loads older than av -> counted vmcnt), issue A(0) ----
#pragma unroll
    for (int b = 0; b < 8; ++b) {
        const int bl = b * 256 + tid;
        const int row = bl >> 4;
        const int cb = (bl & 15) * 8;
        *(bf16x8*)(&ldsW[row * WSTR + cb]) =
            *(const bf16x8*)(&Wb[(size_t)(i0 + row) * D + cb]);
        *(bf16x8*)(&ldsWj[row * WSTR + cb]) =
            *(const bf16x8*)(&Wb[(size_t)(jb * BN + row) * D + cb]);
    }
    float4 av[16];
#pragma unroll
    for (int p = 0; p < 16; ++p)
        av[p] = *(const float4*)(&A[(size_t)(i0 + p * 8 + r8) * N + jb * BN + c4]);

    // sq_i is invariant across the j-loop: hoist (16 VGPRs)
    float sqi[4][4];
#pragma unroll
    for (int ti = 0; ti < 4; ++ti)
#pragma unroll
        for (int r = 0; r < 4; ++r)
            sqi[ti][r] = sq[i0 + wr + ti * 16 + quad * 4 + r];

    asm volatile("s_waitcnt lgkmcnt(0)" ::: "memory");
    __builtin_amdgcn_s_barrier();                 // W tiles visible; av still in flight

    float local = 0.0f;

    for (int t = 0; t < TJ; ++t) {
        const int j0 = (jb + t) * BN;

        // ---- Gram from LDS: frag layout [m=lane&15][k=quad*8+j] ----
        f32x4 acc[4][4] = {};
#pragma unroll
        for (int kc = 0; kc < 4; ++kc) {
            bf16x8 fa[4], fb[4];
#pragma unroll
            for (int u = 0; u < 4; ++u)
                fa[u] = *(const bf16x8*)(&ldsW[(wr + u * 16 + l15) * WSTR + kc * 32 + quad * 8]);
#pragma unroll
            for (int u = 0; u < 4; ++u)
                fb[u] = *(const bf16x8*)(&ldsWj[(wc + u * 16 + l15) * WSTR + kc * 32 + quad * 8]);
#pragma unroll
            for (int ti = 0; ti < 4; ++ti)
#pragma unroll
                for (int tj = 0; tj < 4; ++tj)
                    acc[ti][tj] = __builtin_amdgcn_mfma_f32_16x16x32_bf16(fa[ti], fb[tj], acc[ti][tj], 0, 0, 0);
        }
        asm volatile("s_waitcnt lgkmcnt(0)" ::: "memory");
        __builtin_amdgcn_s_barrier();             // all waves done reading Wj -> reusable

        // ---- dist = sqrt(max(sq_i+sq_j-2g,0)) -> bf16 overlay in Wj region ----
        // C/D mapping (m89-verified): col = lane&15, row = quad*4 + reg
#pragma unroll
        for (int tj = 0; tj < 4; ++tj) {
            const int col = wc + tj * 16 + l15;
            const float sqj = sq[j0 + col];
#pragma unroll
            for (int ti = 0; ti < 4; ++ti)
#pragma unroll
                for (int r = 0; r < 4; ++r) {
                    const int row = wr + ti * 16 + quad * 4 + r;
                    const float d2 = fmaf(-2.0f, acc[ti][tj][r], sqi[ti][r] + sqj);
                    ldsWj[row * WSTR + col] = (__bf16)__builtin_amdgcn_sqrtf(fmaxf(d2, 0.0f));
                }
        }
        asm volatile("s_waitcnt lgkmcnt(0)" ::: "memory");
        __builtin_amdgcn_s_barrier();             // dist visible to all waves

        // ---- consume: av registers (A) x bf16x4 dist from LDS ----
        // compiler inserts the (only) vmcnt wait for av right here, at first use
#pragma unroll
        for (int p = 0; p < 16; ++p) {
            const bf16x4 dv = *(const bf16x4*)(&ldsWj[(p * 8 + r8) * WSTR + c4]);
            local += av[p].x * (float)dv[0] + av[p].y * (float)dv[1]
                   + av[p].z * (float)dv[2] + av[p].w * (float)dv[3];
        }

        if (t + 1 < TJ) {
            const int j1 = (jb + t + 1) * BN;
            // issue Wj(t+1) loads FIRST (older), then A(t+1): the ds_write below
            // then waits at vmcnt(16), keeping all 16 A loads in flight across
            // the next Gram+dist phases.
            bf16x8 wreg[8];
#pragma unroll
            for (int b = 0; b < 8; ++b) {
                const int bl = b * 256 + tid;
                const int row = bl >> 4;
                const int cb = (bl & 15) * 8;
                wreg[b] = *(const bf16x8*)(&Wb[(size_t)(j1 + row) * D + cb]);
            }
#pragma unroll
            for (int p = 0; p < 16; ++p)
                av[p] = *(const float4*)(&A[(size_t)(i0 + p * 8 + r8) * N + j1 + c4]);

            asm volatile("s_waitcnt lgkmcnt(0)" ::: "memory");
            __builtin_amdgcn_s_barrier();         // all consume reads of dist done

#pragma unroll
            for (int b = 0; b < 8; ++b) {
                const int bl = b * 256 + tid;
                const int row = bl >> 4;
                const int cb = (bl & 15) * 8;
                *(bf16x8*)(&ldsWj[row * WSTR + cb]) = wreg[b];
            }
            asm volatile("s_waitcnt lgkmcnt(0)" ::: "memory");
            __builtin_amdgcn_s_barrier();         // Wj(t+1) visible for next Gram
        }
    }

    // ---- block reduce + one atomic per block ----
    for (int off = 32; off > 0; off >>= 1) local += __shfl_down(local, off, 64);
    if (lane == 0) red[wave] = local;
    __syncthreads();
    if (tid == 0) atomicAdd(out, red[0] + red[1] + red[2] + red[3]);
}

extern "C" void kernel_launch(void* const* d_in, const int* in_sizes, int n_in,
                              void* d_out, int out_size, void* d_ws, size_t ws_size,
                              hipStream_t stream) {
    const float* A = (const float*)d_in[0];
    const float* W = (const float*)d_in[1];
    float* out = (float*)d_out;
    float* sq = (float*)d_ws;                         // 32 KB
    __bf16* Wb = (__bf16*)((char*)d_ws + 32 * 1024);  // 2 MB

    prep_kernel<<<N / 4, 256, 0, stream>>>(W, out, sq, Wb);
    lap_kernel<<<512, 256, 0, stream>>>(A, Wb, sq, out);
}

// Round 4
// 355.389 us; speedup vs baseline: 1.1686x; 1.0549x over previous
//
#include <hip/hip_runtime.h>
#include <hip/hip_bf16.h>

#define N 8192
#define D 128
#define BM 128
#define BN 128
#define WSTR 136   // bf16 LDS stride: 272 B/row -> 16B-aligned b128, 2-way banks (free)

typedef __bf16 bf16x8 __attribute__((ext_vector_type(8)));
typedef __bf16 bf16x4 __attribute__((ext_vector_type(4)));
typedef __bf16 bf16x2 __attribute__((ext_vector_type(2)));
typedef float f32x4 __attribute__((ext_vector_type(4)));

// Prep: Wb = bf16(W) ; sq[i] = sum_k W[i][k]^2 ; copy W to out+1 ; zero out[0]
__global__ __launch_bounds__(256) void prep_kernel(const float* __restrict__ W,
                                                   float* __restrict__ out,
                                                   float* __restrict__ sq,
                                                   __bf16* __restrict__ Wb) {
    const int wave = threadIdx.x >> 6;
    const int lane = threadIdx.x & 63;
    const int row = blockIdx.x * 4 + wave;
    const size_t base = (size_t)row * D + lane * 2;
    const float2 v = *(const float2*)(&W[base]);
    out[1 + base] = v.x;           // out+1 is only 4B-aligned; scalar stores
    out[2 + base] = v.y;
    bf16x2 b;
    b[0] = (__bf16)v.x;
    b[1] = (__bf16)v.y;
    *(bf16x2*)(&Wb[base]) = b;
    float s = v.x * v.x + v.y * v.y;
    for (int off = 32; off > 0; off >>= 1) s += __shfl_down(s, off, 64);
    if (lane == 0) sq[row] = s;
    if (row == 0 && threadIdx.x == 0) out[0] = 0.0f;
}

// One-shot 128x128 tile per block (round-0 structure), with TRUE A-prefetch:
//   W staged FIRST (its counted vmcnt waits can't touch A), A float4 loads issued
//   LAST (youngest), raw s_barrier + lgkmcnt-only waits (no vmcnt(0) drain) ->
//   A stays in flight across Gram + dist and is ready at consume.
__global__ __launch_bounds__(256, 2) void lap_kernel(const float* __restrict__ A,
                                                     const __bf16* __restrict__ Wb,
                                                     const float* __restrict__ sq,
                                                     float* __restrict__ out) {
    __shared__ __align__(16) __bf16 ldsW[2 * BM * WSTR];  // Wi | Wj = 69.6 KB
    __bf16* ldsD = ldsW;                                   // dist overlays Wi after Gram
    __shared__ float red[4];

    const int tid = threadIdx.x;
    const int wave = tid >> 6;
    const int lane = tid & 63;
    const int l15 = lane & 15;
    const int quad = lane >> 4;
    const int wr = (wave >> 1) * 64;
    const int wc = (wave & 1) * 64;
    const int i0 = (int)(blockIdx.x >> 6) * BM;
    const int j0 = (int)(blockIdx.x & 63) * BN;

    // ---- 1) stage Wi/Wj (bf16, L2-resident) into LDS, fully coalesced ----
    // Issued BEFORE the A loads: the ds_writes' counted vmcnt waits then only
    // cover W loads, leaving the A loads (issued below, younger) untouched.
#pragma unroll
    for (int b = 0; b < 8; ++b) {
        const int bl = b * 256 + tid;       // linear 16B-block id, consecutive lanes
        const int row = bl >> 4;
        const int cb = (bl & 15) * 8;       // bf16 col
        *(bf16x8*)(&ldsW[row * WSTR + cb]) =
            *(const bf16x8*)(&Wb[(size_t)(i0 + row) * D + cb]);
        *(bf16x8*)(&ldsW[BM * WSTR + row * WSTR + cb]) =
            *(const bf16x8*)(&Wb[(size_t)(j0 + row) * D + cb]);
    }

    // ---- 2) issue ALL 16 A-tile float4 loads (youngest; consumed last) ----
    const int r8 = tid >> 5;          // 0..7
    const int c4 = (tid & 31) * 4;    // 0,4,...,124
    float4 av[16];
#pragma unroll
    for (int p = 0; p < 16; ++p)
        av[p] = *(const float4*)(&A[(size_t)(i0 + p * 8 + r8) * N + j0 + c4]);

    asm volatile("s_waitcnt lgkmcnt(0)" ::: "memory");   // W tiles visible
    __builtin_amdgcn_s_barrier();                        // av still in flight

    // ---- 3) Gram from LDS: frag layout [m=lane&15][k=quad*8+j] ----
    f32x4 acc[4][4] = {};
#pragma unroll
    for (int kc = 0; kc < 4; ++kc) {
        bf16x8 a[4], b[4];
#pragma unroll
        for (int t = 0; t < 4; ++t)
            a[t] = *(const bf16x8*)(&ldsW[(wr + t * 16 + l15) * WSTR + kc * 32 + quad * 8]);
#pragma unroll
        for (int t = 0; t < 4; ++t)
            b[t] = *(const bf16x8*)(&ldsW[BM * WSTR + (wc + t * 16 + l15) * WSTR + kc * 32 + quad * 8]);
#pragma unroll
        for (int ti = 0; ti < 4; ++ti)
#pragma unroll
            for (int tj = 0; tj < 4; ++tj)
                acc[ti][tj] = __builtin_amdgcn_mfma_f32_16x16x32_bf16(a[ti], b[tj], acc[ti][tj], 0, 0, 0);
    }
    asm volatile("s_waitcnt lgkmcnt(0)" ::: "memory");   // all W reads retired
    __builtin_amdgcn_s_barrier();                        // LDS reusable for dist

    // ---- 4) dist = sqrt(max(sq_i+sq_j-2g,0)) -> bf16 LDS (C/D order writes) ----
    // C/D mapping (m89-verified): col = lane&15, row = quad*4 + reg
    float sqi[4][4];
#pragma unroll
    for (int ti = 0; ti < 4; ++ti)
#pragma unroll
        for (int r = 0; r < 4; ++r)
            sqi[ti][r] = sq[i0 + wr + ti * 16 + quad * 4 + r];

#pragma unroll
    for (int ti = 0; ti < 4; ++ti) {
#pragma unroll
        for (int tj = 0; tj < 4; ++tj) {
            const int col = wc + tj * 16 + l15;
            const float sqj = sq[j0 + col];
#pragma unroll
            for (int r = 0; r < 4; ++r) {
                const int row = wr + ti * 16 + quad * 4 + r;
                const float d2 = fmaf(-2.0f, acc[ti][tj][r], sqi[ti][r] + sqj);
                ldsD[row * WSTR + col] = (__bf16)__builtin_amdgcn_sqrtf(fmaxf(d2, 0.0f));
            }
        }
    }
    asm volatile("s_waitcnt lgkmcnt(0)" ::: "memory");   // dist visible
    __builtin_amdgcn_s_barrier();

    // ---- 5) consume: av registers (A) x bf16x4 dist from LDS ----
    // first av use -> compiler's counted vmcnt wait lands here; av had
    // Gram+dist (~2K cycles) of cover, so the wait is ~free.
    float local = 0.0f;
#pragma unroll
    for (int p = 0; p < 16; ++p) {
        const bf16x4 dv = *(const bf16x4*)(&ldsD[(p * 8 + r8) * WSTR + c4]);
        local += av[p].x * (float)dv[0] + av[p].y * (float)dv[1]
               + av[p].z * (float)dv[2] + av[p].w * (float)dv[3];
    }

    // ---- block reduce + one atomic per block ----
    for (int off = 32; off > 0; off >>= 1) local += __shfl_down(local, off, 64);
    if (lane == 0) red[wave] = local;
    __syncthreads();
    if (tid == 0) atomicAdd(out, red[0] + red[1] + red[2] + red[3]);
}

extern "C" void kernel_launch(void* const* d_in, const int* in_sizes, int n_in,
                              void* d_out, int out_size, void* d_ws, size_t ws_size,
                              hipStream_t stream) {
    const float* A = (const float*)d_in[0];
    const float* W = (const float*)d_in[1];
    float* out = (float*)d_out;
    float* sq = (float*)d_ws;                         // 32 KB
    __bf16* Wb = (__bf16*)((char*)d_ws + 32 * 1024);  // 2 MB

    prep_kernel<<<N / 4, 256, 0, stream>>>(W, out, sq, Wb);
    lap_kernel<<<4096, 256, 0, stream>>>(A, Wb, sq, out);
}